// Round 1
// baseline (394.710 us; speedup 1.0000x reference)
//
#include <hip/hip_runtime.h>

constexpr int FIN = 512;
constexpr int FH  = 128;
constexpr int FO  = 64;

// ---------------- degree / normalization ----------------

__global__ void count_kernel(const int* __restrict__ dst, int* __restrict__ cnt, int E) {
    int i = blockIdx.x * blockDim.x + threadIdx.x;
    if (i < E) atomicAdd(&cnt[dst[i]], 1);
}

__global__ void dinv_kernel(const int* __restrict__ cnt, float* __restrict__ dinv, int n) {
    int i = blockIdx.x * blockDim.x + threadIdx.x;
    if (i < n) dinv[i] = rsqrtf((float)(cnt[i] + 1));  // deg = in-degree + self-loop
}

// ---------------- exclusive scan (3 kernels, 1024 elems/block) ----------------

__global__ void scan1_kernel(const int* __restrict__ cnt, int* __restrict__ offs,
                             int* __restrict__ bsum, int n) {
    __shared__ int sdata[256];
    int t = threadIdx.x;
    int base = blockIdx.x * 1024 + t * 4;
    int4 c = make_int4(0, 0, 0, 0);
    if (base + 3 < n) {
        c = *(const int4*)(cnt + base);
    } else {
        if (base + 0 < n) c.x = cnt[base + 0];
        if (base + 1 < n) c.y = cnt[base + 1];
        if (base + 2 < n) c.z = cnt[base + 2];
        if (base + 3 < n) c.w = cnt[base + 3];
    }
    int s0 = c.x + c.y + c.z + c.w;
    sdata[t] = s0;
    __syncthreads();
    for (int off = 1; off < 256; off <<= 1) {
        int v = (t >= off) ? sdata[t - off] : 0;
        __syncthreads();
        sdata[t] += v;
        __syncthreads();
    }
    int excl = sdata[t] - s0;
    if (t == 255) bsum[blockIdx.x] = sdata[255];
    if (base + 0 < n) offs[base + 0] = excl;
    if (base + 1 < n) offs[base + 1] = excl + c.x;
    if (base + 2 < n) offs[base + 2] = excl + c.x + c.y;
    if (base + 3 < n) offs[base + 3] = excl + c.x + c.y + c.z;
}

__global__ void scan2_kernel(int* __restrict__ bsum, int nb) {
    __shared__ int sdata[256];
    int t = threadIdx.x;
    int v = (t < nb) ? bsum[t] : 0;
    sdata[t] = v;
    __syncthreads();
    for (int off = 1; off < 256; off <<= 1) {
        int u = (t >= off) ? sdata[t - off] : 0;
        __syncthreads();
        sdata[t] += u;
        __syncthreads();
    }
    if (t < nb) bsum[t] = sdata[t] - v;  // exclusive
}

__global__ void scan3_kernel(int* __restrict__ offs, const int* __restrict__ bsum,
                             int n, int E) {
    int i = blockIdx.x * blockDim.x + threadIdx.x;
    if (i < n) offs[i] += bsum[i >> 10];
    if (i == 0) offs[n] = E;
}

// ---------------- CSR fill (counting sort by dst) ----------------

__global__ void fill_kernel(const int* __restrict__ src, const int* __restrict__ dst,
                            const float* __restrict__ dinv, const int* __restrict__ offs,
                            int* __restrict__ cursor, int2* __restrict__ esort, int E) {
    int i = blockIdx.x * blockDim.x + threadIdx.x;
    if (i < E) {
        int s = src[i];
        int d = dst[i];
        int pos = offs[d] + atomicAdd(&cursor[d], 1);
        float w = dinv[s] * dinv[d];
        esort[pos] = make_int2(s, __float_as_int(w));
    }
}

// ---------------- SpMM gather: out[i] = dinv[i]^2*h[i] + sum_e norm_e * h[src_e] ---

__global__ void spmm_kernel(const float* __restrict__ hin, const int* __restrict__ offs,
                            const int2* __restrict__ esort, const float* __restrict__ dinv,
                            const float* __restrict__ bias, float* __restrict__ hout,
                            int n, int relu) {
    int gid = blockIdx.x * blockDim.x + threadIdx.x;
    int node = gid >> 6;            // one 64-lane wave per node
    int lane = threadIdx.x & 63;    // lane handles channels 2*lane, 2*lane+1
    if (node >= n) return;
    const float2* h2 = (const float2*)hin;
    float di = dinv[node];
    float2 hv = h2[(size_t)node * 64 + lane];
    float ax = di * di * hv.x;
    float ay = di * di * hv.y;
    int p = offs[node];
    int end = offs[node + 1];
    for (; p + 4 <= end; p += 4) {
        int2 e0 = esort[p + 0];
        int2 e1 = esort[p + 1];
        int2 e2 = esort[p + 2];
        int2 e3 = esort[p + 3];
        float2 v0 = h2[(size_t)e0.x * 64 + lane];
        float2 v1 = h2[(size_t)e1.x * 64 + lane];
        float2 v2 = h2[(size_t)e2.x * 64 + lane];
        float2 v3 = h2[(size_t)e3.x * 64 + lane];
        float w0 = __int_as_float(e0.y), w1 = __int_as_float(e1.y);
        float w2 = __int_as_float(e2.y), w3 = __int_as_float(e3.y);
        ax = fmaf(w0, v0.x, ax); ay = fmaf(w0, v0.y, ay);
        ax = fmaf(w1, v1.x, ax); ay = fmaf(w1, v1.y, ay);
        ax = fmaf(w2, v2.x, ax); ay = fmaf(w2, v2.y, ay);
        ax = fmaf(w3, v3.x, ax); ay = fmaf(w3, v3.y, ay);
    }
    for (; p < end; ++p) {
        int2 e = esort[p];
        float2 v = h2[(size_t)e.x * 64 + lane];
        float w = __int_as_float(e.y);
        ax = fmaf(w, v.x, ax); ay = fmaf(w, v.y, ay);
    }
    if (bias) {
        float2 b = ((const float2*)bias)[lane];
        ax += b.x; ay += b.y;
    }
    if (relu) { ax = fmaxf(ax, 0.f); ay = fmaxf(ay, 0.f); }
    float2 o; o.x = ax; o.y = ay;
    ((float2*)hout)[(size_t)node * 64 + lane] = o;
}

// ---------------- GEMM: out[M,128] = X[M,K] @ W[128,K]^T ----------------
// mode 0: outA[M,128] = X@W^T (Wlo rows 0-63, Whi rows 64-127), no bias
// mode 1: outA[M,64] = X@Wlo^T + biasA ; outB[M,64] = X@Whi^T + biasB

__global__ __launch_bounds__(256) void gemm_kernel(
    const float* __restrict__ X, const float* __restrict__ Wlo, const float* __restrict__ Whi,
    float* __restrict__ outA, float* __restrict__ outB,
    const float* __restrict__ biasA, const float* __restrict__ biasB,
    int M, int K, int mode) {
    __shared__ __align__(16) float As[16][65];
    __shared__ __align__(16) float Bs[16][132];
    int tid = threadIdx.x;
    int tx = tid & 15;      // 16 col groups
    int ty = tid >> 4;      // 16 row groups
    int row0 = blockIdx.x * 64;

    float acc[4][8];
    #pragma unroll
    for (int r = 0; r < 4; ++r)
        #pragma unroll
        for (int c = 0; c < 8; ++c) acc[r][c] = 0.f;

    int lm = tid >> 2;            // 0..63
    int lk = (tid & 3) * 4;       // 0,4,8,12

    for (int k0 = 0; k0 < K; k0 += 16) {
        // stage A tile 64x16
        {
            int row = row0 + lm;
            float4 a = make_float4(0, 0, 0, 0);
            if (row < M) a = *(const float4*)(X + (size_t)row * K + k0 + lk);
            As[lk + 0][lm] = a.x; As[lk + 1][lm] = a.y;
            As[lk + 2][lm] = a.z; As[lk + 3][lm] = a.w;
        }
        // stage B tile 16x128 (cols 0-63 from Wlo, 64-127 from Whi)
        {
            float4 b0 = *(const float4*)(Wlo + (size_t)lm * K + k0 + lk);
            float4 b1 = *(const float4*)(Whi + (size_t)lm * K + k0 + lk);
            Bs[lk + 0][lm] = b0.x; Bs[lk + 1][lm] = b0.y;
            Bs[lk + 2][lm] = b0.z; Bs[lk + 3][lm] = b0.w;
            Bs[lk + 0][lm + 64] = b1.x; Bs[lk + 1][lm + 64] = b1.y;
            Bs[lk + 2][lm + 64] = b1.z; Bs[lk + 3][lm + 64] = b1.w;
        }
        __syncthreads();
        #pragma unroll
        for (int k = 0; k < 16; ++k) {
            float a[4];
            a[0] = As[k][ty * 4 + 0];
            a[1] = As[k][ty * 4 + 1];
            a[2] = As[k][ty * 4 + 2];
            a[3] = As[k][ty * 4 + 3];
            const float4 bl = *(const float4*)&Bs[k][tx * 4];
            const float4 bh = *(const float4*)&Bs[k][64 + tx * 4];
            float b[8] = {bl.x, bl.y, bl.z, bl.w, bh.x, bh.y, bh.z, bh.w};
            #pragma unroll
            for (int r = 0; r < 4; ++r)
                #pragma unroll
                for (int c = 0; c < 8; ++c)
                    acc[r][c] = fmaf(a[r], b[c], acc[r][c]);
        }
        __syncthreads();
    }

    if (mode == 0) {
        #pragma unroll
        for (int r = 0; r < 4; ++r) {
            int row = row0 + ty * 4 + r;
            if (row >= M) continue;
            float4 lo = make_float4(acc[r][0], acc[r][1], acc[r][2], acc[r][3]);
            float4 hi = make_float4(acc[r][4], acc[r][5], acc[r][6], acc[r][7]);
            *(float4*)(outA + (size_t)row * 128 + tx * 4) = lo;
            *(float4*)(outA + (size_t)row * 128 + 64 + tx * 4) = hi;
        }
    } else {
        float4 ba = *(const float4*)(biasA + tx * 4);
        float4 bb = *(const float4*)(biasB + tx * 4);
        #pragma unroll
        for (int r = 0; r < 4; ++r) {
            int row = row0 + ty * 4 + r;
            if (row >= M) continue;
            float4 lo = make_float4(acc[r][0] + ba.x, acc[r][1] + ba.y,
                                    acc[r][2] + ba.z, acc[r][3] + ba.w);
            float4 hi = make_float4(acc[r][4] + bb.x, acc[r][5] + bb.y,
                                    acc[r][6] + bb.z, acc[r][7] + bb.w);
            *(float4*)(outA + (size_t)row * 64 + tx * 4) = lo;
            *(float4*)(outB + (size_t)row * 64 + tx * 4) = hi;
        }
    }
}

// ---------------- launch ----------------

extern "C" void kernel_launch(void* const* d_in, const int* in_sizes, int n_in,
                              void* d_out, int out_size, void* d_ws, size_t ws_size,
                              hipStream_t stream) {
    const float* x   = (const float*)d_in[0];
    const int*   ei  = (const int*)d_in[1];
    const float* W1  = (const float*)d_in[2];
    const float* b1  = (const float*)d_in[3];
    const float* Wmu = (const float*)d_in[4];
    const float* bmu = (const float*)d_in[5];
    const float* Wlg = (const float*)d_in[6];
    const float* blg = (const float*)d_in[7];

    const int n = in_sizes[0] / FIN;   // 50000
    const int E = in_sizes[1] / 2;     // 800000
    const int* src = ei;
    const int* dst = ei + E;

    char* ws = (char*)d_ws;
    size_t off = 0;
    auto alloc = [&](size_t bytes) -> void* {
        void* p = ws + off;
        off = (off + bytes + 255) & ~((size_t)255);
        return p;
    };
    int*   cnt    = (int*)  alloc((size_t)n * 4);
    int*   offs   = (int*)  alloc((size_t)(n + 1) * 4);
    int*   cursor = (int*)  alloc((size_t)n * 4);
    int*   bsum   = (int*)  alloc(1024);
    float* dinv   = (float*)alloc((size_t)n * 4);
    int2*  esort  = (int2*) alloc((size_t)E * 8);
    float* h      = (float*)alloc((size_t)n * FH * 4);
    float* h1     = (float*)alloc((size_t)n * FH * 4);

    hipMemsetAsync(cnt, 0, (size_t)n * 4, stream);
    hipMemsetAsync(cursor, 0, (size_t)n * 4, stream);

    count_kernel<<<(E + 255) / 256, 256, 0, stream>>>(dst, cnt, E);
    dinv_kernel<<<(n + 255) / 256, 256, 0, stream>>>(cnt, dinv, n);

    int nb = (n + 1023) / 1024;  // 49
    scan1_kernel<<<nb, 256, 0, stream>>>(cnt, offs, bsum, n);
    scan2_kernel<<<1, 256, 0, stream>>>(bsum, nb);
    scan3_kernel<<<(n + 255) / 256, 256, 0, stream>>>(offs, bsum, n, E);

    fill_kernel<<<(E + 255) / 256, 256, 0, stream>>>(src, dst, dinv, offs, cursor, esort, E);

    // layer 1: h = x @ W1^T
    gemm_kernel<<<(n + 63) / 64, 256, 0, stream>>>(
        x, W1, W1 + (size_t)64 * FIN, h, nullptr, nullptr, nullptr, n, FIN, 0);
    // h1 = relu(A_norm @ h + b1)
    spmm_kernel<<<(n + 3) / 4, 256, 0, stream>>>(h, offs, esort, dinv, b1, h1, n, 1);
    // ah2 = A_norm @ h1 (reuse h buffer)
    spmm_kernel<<<(n + 3) / 4, 256, 0, stream>>>(h1, offs, esort, dinv, nullptr, h, n, 0);
    // mu / logstd = ah2 @ W^T + b
    float* outmu = (float*)d_out;
    float* outlg = outmu + (size_t)n * FO;
    gemm_kernel<<<(n + 63) / 64, 256, 0, stream>>>(
        h, Wmu, Wlg, outmu, outlg, bmu, blg, n, FH, 1);
}

// Round 2
// 279.481 us; speedup vs baseline: 1.4123x; 1.4123x over previous
//
#include <hip/hip_runtime.h>

constexpr int FIN = 512;
constexpr int FH  = 128;
constexpr int FO  = 64;

typedef short short8 __attribute__((ext_vector_type(8)));
typedef float f32x4 __attribute__((ext_vector_type(4)));

__device__ __forceinline__ unsigned short f2bf(float f) {
    unsigned u = __float_as_uint(f);
    u += 0x7fffu + ((u >> 16) & 1u);   // RNE
    return (unsigned short)(u >> 16);
}

// ---------------- degree / normalization ----------------

__global__ void count_kernel(const int* __restrict__ dst, int* __restrict__ cnt, int E) {
    int i = blockIdx.x * blockDim.x + threadIdx.x;
    if (i < E) atomicAdd(&cnt[dst[i]], 1);
}

__global__ void dinv_kernel(const int* __restrict__ cnt, float* __restrict__ dinv, int n) {
    int i = blockIdx.x * blockDim.x + threadIdx.x;
    if (i < n) dinv[i] = rsqrtf((float)(cnt[i] + 1));  // deg = in-degree + self-loop
}

// ---------------- exclusive scan (3 kernels, 1024 elems/block) ----------------

__global__ void scan1_kernel(const int* __restrict__ cnt, int* __restrict__ offs,
                             int* __restrict__ bsum, int n) {
    __shared__ int sdata[256];
    int t = threadIdx.x;
    int base = blockIdx.x * 1024 + t * 4;
    int4 c = make_int4(0, 0, 0, 0);
    if (base + 3 < n) {
        c = *(const int4*)(cnt + base);
    } else {
        if (base + 0 < n) c.x = cnt[base + 0];
        if (base + 1 < n) c.y = cnt[base + 1];
        if (base + 2 < n) c.z = cnt[base + 2];
        if (base + 3 < n) c.w = cnt[base + 3];
    }
    int s0 = c.x + c.y + c.z + c.w;
    sdata[t] = s0;
    __syncthreads();
    for (int off = 1; off < 256; off <<= 1) {
        int v = (t >= off) ? sdata[t - off] : 0;
        __syncthreads();
        sdata[t] += v;
        __syncthreads();
    }
    int excl = sdata[t] - s0;
    if (t == 255) bsum[blockIdx.x] = sdata[255];
    if (base + 0 < n) offs[base + 0] = excl;
    if (base + 1 < n) offs[base + 1] = excl + c.x;
    if (base + 2 < n) offs[base + 2] = excl + c.x + c.y;
    if (base + 3 < n) offs[base + 3] = excl + c.x + c.y + c.z;
}

__global__ void scan2_kernel(int* __restrict__ bsum, int nb) {
    __shared__ int sdata[256];
    int t = threadIdx.x;
    int v = (t < nb) ? bsum[t] : 0;
    sdata[t] = v;
    __syncthreads();
    for (int off = 1; off < 256; off <<= 1) {
        int u = (t >= off) ? sdata[t - off] : 0;
        __syncthreads();
        sdata[t] += u;
        __syncthreads();
    }
    if (t < nb) bsum[t] = sdata[t] - v;  // exclusive
}

__global__ void scan3_kernel(int* __restrict__ offs, const int* __restrict__ bsum,
                             int n, int E) {
    int i = blockIdx.x * blockDim.x + threadIdx.x;
    if (i < n) offs[i] += bsum[i >> 10];
    if (i == 0) offs[n] = E;
}

// ---------------- CSR fill (counting sort by dst) ----------------

__global__ void fill_kernel(const int* __restrict__ src, const int* __restrict__ dst,
                            const float* __restrict__ dinv, const int* __restrict__ offs,
                            int* __restrict__ cursor, int2* __restrict__ esort, int E) {
    int i = blockIdx.x * blockDim.x + threadIdx.x;
    if (i < E) {
        int s = src[i];
        int d = dst[i];
        int pos = offs[d] + atomicAdd(&cursor[d], 1);
        float w = dinv[s] * dinv[d];
        esort[pos] = make_int2(s, __float_as_int(w));
    }
}

// ---------------- SpMM gather: out[i] = dinv[i]^2*h[i] + sum_e norm_e * h[src_e] ---

__global__ void spmm_kernel(const float* __restrict__ hin, const int* __restrict__ offs,
                            const int2* __restrict__ esort, const float* __restrict__ dinv,
                            const float* __restrict__ bias, float* __restrict__ hout,
                            int n, int relu) {
    int gid = blockIdx.x * blockDim.x + threadIdx.x;
    int node = gid >> 6;            // one 64-lane wave per node
    int lane = threadIdx.x & 63;    // lane handles channels 2*lane, 2*lane+1
    if (node >= n) return;
    const float2* h2 = (const float2*)hin;
    float di = dinv[node];
    float2 hv = h2[(size_t)node * 64 + lane];
    float ax = di * di * hv.x;
    float ay = di * di * hv.y;
    int p = offs[node];
    int end = offs[node + 1];
    for (; p + 4 <= end; p += 4) {
        int2 e0 = esort[p + 0];
        int2 e1 = esort[p + 1];
        int2 e2 = esort[p + 2];
        int2 e3 = esort[p + 3];
        float2 v0 = h2[(size_t)e0.x * 64 + lane];
        float2 v1 = h2[(size_t)e1.x * 64 + lane];
        float2 v2 = h2[(size_t)e2.x * 64 + lane];
        float2 v3 = h2[(size_t)e3.x * 64 + lane];
        float w0 = __int_as_float(e0.y), w1 = __int_as_float(e1.y);
        float w2 = __int_as_float(e2.y), w3 = __int_as_float(e3.y);
        ax = fmaf(w0, v0.x, ax); ay = fmaf(w0, v0.y, ay);
        ax = fmaf(w1, v1.x, ax); ay = fmaf(w1, v1.y, ay);
        ax = fmaf(w2, v2.x, ax); ay = fmaf(w2, v2.y, ay);
        ax = fmaf(w3, v3.x, ax); ay = fmaf(w3, v3.y, ay);
    }
    for (; p < end; ++p) {
        int2 e = esort[p];
        float2 v = h2[(size_t)e.x * 64 + lane];
        float w = __int_as_float(e.y);
        ax = fmaf(w, v.x, ax); ay = fmaf(w, v.y, ay);
    }
    if (bias) {
        float2 b = ((const float2*)bias)[lane];
        ax += b.x; ay += b.y;
    }
    if (relu) { ax = fmaxf(ax, 0.f); ay = fmaxf(ay, 0.f); }
    float2 o; o.x = ax; o.y = ay;
    ((float2*)hout)[(size_t)node * 64 + lane] = o;
}

// ---------------- bf16 MFMA GEMM: h[M,128] = X[M,512] @ W[128,512]^T ----------------
// 256 threads = 4 waves (2x2 wave grid, 64x64 output each). Tile 128x128, BK=64.
// Reg-stage fp32 -> cvt bf16 -> XOR-swizzled LDS (T2); mfma_f32_16x16x32_bf16.

__global__ __launch_bounds__(256) void gemm1_kernel(
    const float* __restrict__ X, const float* __restrict__ W,
    float* __restrict__ out, int M) {
    __shared__ __align__(16) unsigned short As[128 * 64];  // [row][k] swizzled, 16KB
    __shared__ __align__(16) unsigned short Bs[128 * 64];

    int tid = threadIdx.x;
    int lane = tid & 63;
    int wid = tid >> 6;
    int wr = wid >> 1, wc = wid & 1;      // wave -> 64x64 output sub-tile
    int fr = lane & 15, fq = lane >> 4;   // fragment row / quarter
    int row0 = blockIdx.x * 128;

    f32x4 acc[4][4] = {};

    for (int k0 = 0; k0 < FIN; k0 += 64) {
        #pragma unroll
        for (int i = 0; i < 8; ++i) {
            int f = tid + 256 * i;
            int r = f >> 4;          // 0..127 tile row
            int kq = f & 15;         // float4 index within 64-k row
            int boff = r * 128 + ((((kq >> 1) ^ (r & 7)) << 4) | ((kq & 1) << 3));
            // A tile (X rows)
            int row = row0 + r;
            float4 va = make_float4(0.f, 0.f, 0.f, 0.f);
            if (row < M) va = *(const float4*)(X + (size_t)row * FIN + k0 + kq * 4);
            ushort4 pa;
            pa.x = f2bf(va.x); pa.y = f2bf(va.y); pa.z = f2bf(va.z); pa.w = f2bf(va.w);
            *(ushort4*)((char*)As + boff) = pa;
            // B tile (W rows, all 128 output channels)
            float4 vb = *(const float4*)(W + (size_t)r * FIN + k0 + kq * 4);
            ushort4 pb;
            pb.x = f2bf(vb.x); pb.y = f2bf(vb.y); pb.z = f2bf(vb.z); pb.w = f2bf(vb.w);
            *(ushort4*)((char*)Bs + boff) = pb;
        }
        __syncthreads();

        #pragma unroll
        for (int ks = 0; ks < 2; ++ks) {
            short8 af[4], bf[4];
            #pragma unroll
            for (int m = 0; m < 4; ++m) {
                int r = wr * 64 + m * 16 + fr;
                int slot = (ks * 4 + fq) ^ (fr & 7);
                af[m] = *(const short8*)((const char*)As + r * 128 + (slot << 4));
            }
            #pragma unroll
            for (int nn = 0; nn < 4; ++nn) {
                int r = wc * 64 + nn * 16 + fr;
                int slot = (ks * 4 + fq) ^ (fr & 7);
                bf[nn] = *(const short8*)((const char*)Bs + r * 128 + (slot << 4));
            }
            #pragma unroll
            for (int m = 0; m < 4; ++m)
                #pragma unroll
                for (int nn = 0; nn < 4; ++nn)
                    acc[m][nn] = __builtin_amdgcn_mfma_f32_16x16x32_bf16(
                        af[m], bf[nn], acc[m][nn], 0, 0, 0);
        }
        __syncthreads();
    }

    // C/D layout: col = lane&15, row = (lane>>4)*4 + j
    #pragma unroll
    for (int m = 0; m < 4; ++m) {
        #pragma unroll
        for (int nn = 0; nn < 4; ++nn) {
            int col = wc * 64 + nn * 16 + fr;
            int rbase = row0 + wr * 64 + m * 16 + fq * 4;
            #pragma unroll
            for (int j = 0; j < 4; ++j) {
                int row = rbase + j;
                if (row < M) out[(size_t)row * FH + col] = acc[m][nn][j];
            }
        }
    }
}

// ---------------- fp32 GEMM (layer 2/3 heads): K=128, split outputs ----------------

__global__ __launch_bounds__(256) void gemm_kernel(
    const float* __restrict__ X, const float* __restrict__ Wlo, const float* __restrict__ Whi,
    float* __restrict__ outA, float* __restrict__ outB,
    const float* __restrict__ biasA, const float* __restrict__ biasB,
    int M, int K) {
    __shared__ __align__(16) float As[16][65];
    __shared__ __align__(16) float Bs[16][132];
    int tid = threadIdx.x;
    int tx = tid & 15;      // 16 col groups
    int ty = tid >> 4;      // 16 row groups
    int row0 = blockIdx.x * 64;

    float acc[4][8];
    #pragma unroll
    for (int r = 0; r < 4; ++r)
        #pragma unroll
        for (int c = 0; c < 8; ++c) acc[r][c] = 0.f;

    int lm = tid >> 2;            // 0..63
    int lk = (tid & 3) * 4;       // 0,4,8,12

    for (int k0 = 0; k0 < K; k0 += 16) {
        {
            int row = row0 + lm;
            float4 a = make_float4(0, 0, 0, 0);
            if (row < M) a = *(const float4*)(X + (size_t)row * K + k0 + lk);
            As[lk + 0][lm] = a.x; As[lk + 1][lm] = a.y;
            As[lk + 2][lm] = a.z; As[lk + 3][lm] = a.w;
        }
        {
            float4 b0 = *(const float4*)(Wlo + (size_t)lm * K + k0 + lk);
            float4 b1 = *(const float4*)(Whi + (size_t)lm * K + k0 + lk);
            Bs[lk + 0][lm] = b0.x; Bs[lk + 1][lm] = b0.y;
            Bs[lk + 2][lm] = b0.z; Bs[lk + 3][lm] = b0.w;
            Bs[lk + 0][lm + 64] = b1.x; Bs[lk + 1][lm + 64] = b1.y;
            Bs[lk + 2][lm + 64] = b1.z; Bs[lk + 3][lm + 64] = b1.w;
        }
        __syncthreads();
        #pragma unroll
        for (int k = 0; k < 16; ++k) {
            float a[4];
            a[0] = As[k][ty * 4 + 0];
            a[1] = As[k][ty * 4 + 1];
            a[2] = As[k][ty * 4 + 2];
            a[3] = As[k][ty * 4 + 3];
            const float4 bl = *(const float4*)&Bs[k][tx * 4];
            const float4 bh = *(const float4*)&Bs[k][64 + tx * 4];
            float b[8] = {bl.x, bl.y, bl.z, bl.w, bh.x, bh.y, bh.z, bh.w};
            #pragma unroll
            for (int r = 0; r < 4; ++r)
                #pragma unroll
                for (int c = 0; c < 8; ++c)
                    acc[r][c] = fmaf(a[r], b[c], acc[r][c]);
        }
        __syncthreads();
    }

    float4 ba = *(const float4*)(biasA + tx * 4);
    float4 bb = *(const float4*)(biasB + tx * 4);
    #pragma unroll
    for (int r = 0; r < 4; ++r) {
        int row = row0 + ty * 4 + r;
        if (row >= M) continue;
        float4 lo = make_float4(acc[r][0] + ba.x, acc[r][1] + ba.y,
                                acc[r][2] + ba.z, acc[r][3] + ba.w);
        float4 hi = make_float4(acc[r][4] + bb.x, acc[r][5] + bb.y,
                                acc[r][6] + bb.z, acc[r][7] + bb.w);
        *(float4*)(outA + (size_t)row * 64 + tx * 4) = lo;
        *(float4*)(outB + (size_t)row * 64 + tx * 4) = hi;
    }
}

// ---------------- launch ----------------

extern "C" void kernel_launch(void* const* d_in, const int* in_sizes, int n_in,
                              void* d_out, int out_size, void* d_ws, size_t ws_size,
                              hipStream_t stream) {
    const float* x   = (const float*)d_in[0];
    const int*   ei  = (const int*)d_in[1];
    const float* W1  = (const float*)d_in[2];
    const float* b1  = (const float*)d_in[3];
    const float* Wmu = (const float*)d_in[4];
    const float* bmu = (const float*)d_in[5];
    const float* Wlg = (const float*)d_in[6];
    const float* blg = (const float*)d_in[7];

    const int n = in_sizes[0] / FIN;   // 50000
    const int E = in_sizes[1] / 2;     // 800000
    const int* src = ei;
    const int* dst = ei + E;

    char* ws = (char*)d_ws;
    size_t off = 0;
    auto alloc = [&](size_t bytes) -> void* {
        void* p = ws + off;
        off = (off + bytes + 255) & ~((size_t)255);
        return p;
    };
    int*   cnt    = (int*)  alloc((size_t)n * 4);
    int*   offs   = (int*)  alloc((size_t)(n + 1) * 4);
    int*   cursor = (int*)  alloc((size_t)n * 4);
    int*   bsum   = (int*)  alloc(1024);
    float* dinv   = (float*)alloc((size_t)n * 4);
    int2*  esort  = (int2*) alloc((size_t)E * 8);
    float* h      = (float*)alloc((size_t)n * FH * 4);
    float* h1     = (float*)alloc((size_t)n * FH * 4);

    hipMemsetAsync(cnt, 0, (size_t)n * 4, stream);
    hipMemsetAsync(cursor, 0, (size_t)n * 4, stream);

    count_kernel<<<(E + 255) / 256, 256, 0, stream>>>(dst, cnt, E);
    dinv_kernel<<<(n + 255) / 256, 256, 0, stream>>>(cnt, dinv, n);

    int nb = (n + 1023) / 1024;  // 49
    scan1_kernel<<<nb, 256, 0, stream>>>(cnt, offs, bsum, n);
    scan2_kernel<<<1, 256, 0, stream>>>(bsum, nb);
    scan3_kernel<<<(n + 255) / 256, 256, 0, stream>>>(offs, bsum, n, E);

    fill_kernel<<<(E + 255) / 256, 256, 0, stream>>>(src, dst, dinv, offs, cursor, esort, E);

    // layer 1: h = x @ W1^T   (bf16 MFMA, fused fp32->bf16 staging)
    gemm1_kernel<<<(n + 127) / 128, 256, 0, stream>>>(x, W1, h, n);
    // h1 = relu(A_norm @ h + b1)
    spmm_kernel<<<(n + 3) / 4, 256, 0, stream>>>(h, offs, esort, dinv, b1, h1, n, 1);
    // ah2 = A_norm @ h1 (reuse h buffer)
    spmm_kernel<<<(n + 3) / 4, 256, 0, stream>>>(h1, offs, esort, dinv, nullptr, h, n, 0);
    // mu / logstd = ah2 @ W^T + b
    float* outmu = (float*)d_out;
    float* outlg = outmu + (size_t)n * FO;
    gemm_kernel<<<(n + 63) / 64, 256, 0, stream>>>(
        h, Wmu, Wlg, outmu, outlg, bmu, blg, n, FH);
}